// Round 2
// baseline (1265.442 us; speedup 1.0000x reference)
//
#include <hip/hip_runtime.h>
#include <hip/hip_bf16.h>

// GPT forward: B=2, T=1024, D=1024, H=16, HD=64, L=4, V=32000
// fp32 residual stream + LN; bf16 MFMA GEMMs (16x16x32) with fp32 acc.
// Weights transposed+converted to bf16 B^T [N,K] layout in d_ws each call.
// R2: global_load_lds(16B) staging w/ source-side XOR swizzle (m97/m173 pattern),
//     XCD-chunked m-fastest grid swizzle for B-panel L2 reuse.

typedef __attribute__((ext_vector_type(8))) short s16x8;
typedef __attribute__((ext_vector_type(4))) float fx4;

__device__ __forceinline__ unsigned short f2bf(float f) {
    union { float f; unsigned int u; } v; v.f = f;
    unsigned int r = v.u + 0x7FFFu + ((v.u >> 16) & 1u);
    return (unsigned short)(r >> 16);
}

__device__ __forceinline__ void gload16(const short* g, short* l) {
    __builtin_amdgcn_global_load_lds((const __attribute__((address_space(1))) void*)g,
                                     (__attribute__((address_space(3))) void*)l, 16, 0, 0);
}

// ---------------- embedding ----------------
__global__ __launch_bounds__(256) void k_embed(const int* __restrict__ idx,
                                               const float* __restrict__ tok,
                                               const float* __restrict__ pos,
                                               float* __restrict__ x) {
    int r = blockIdx.x;
    int t = r & 1023;
    int tokid = idx[r];
    const float4* a = (const float4*)(tok + (size_t)tokid * 1024);
    const float4* p = (const float4*)(pos + (size_t)t * 1024);
    float4* o = (float4*)(x + (size_t)r * 1024);
    int i = threadIdx.x;
    float4 va = a[i], vp = p[i];
    va.x += vp.x; va.y += vp.y; va.z += vp.z; va.w += vp.w;
    o[i] = va;
}

// ---------------- layernorm (row of 1024), bf16 out ----------------
__global__ __launch_bounds__(256) void k_ln(const float* __restrict__ x,
                                            const float* __restrict__ w,
                                            const float* __restrict__ b,
                                            short* __restrict__ out) {
    int r = blockIdx.x;
    int tid = threadIdx.x;
    float4 v = ((const float4*)(x + (size_t)r * 1024))[tid];
    float s = v.x + v.y + v.z + v.w;
    float ss = v.x*v.x + v.y*v.y + v.z*v.z + v.w*v.w;
    __shared__ float red[8];
    #pragma unroll
    for (int off = 32; off; off >>= 1) { s += __shfl_down(s, off); ss += __shfl_down(ss, off); }
    int wid = tid >> 6;
    if ((tid & 63) == 0) { red[wid] = s; red[4 + wid] = ss; }
    __syncthreads();
    s = red[0] + red[1] + red[2] + red[3];
    ss = red[4] + red[5] + red[6] + red[7];
    float mean = s * (1.0f / 1024.0f);
    float var = ss * (1.0f / 1024.0f) - mean * mean;
    float rstd = rsqrtf(var + 1e-5f);
    float4 wv = ((const float4*)w)[tid];
    float4 bv = ((const float4*)b)[tid];
    union { unsigned short us[4]; unsigned long long ll; } pk;
    pk.us[0] = f2bf((v.x - mean) * rstd * wv.x + bv.x);
    pk.us[1] = f2bf((v.y - mean) * rstd * wv.y + bv.y);
    pk.us[2] = f2bf((v.z - mean) * rstd * wv.z + bv.z);
    pk.us[3] = f2bf((v.w - mean) * rstd * wv.w + bv.w);
    ((unsigned long long*)(out + (size_t)r * 1024))[tid] = pk.ll;
}

// ---------------- transpose + convert: in f32 [K,N] -> out bf16 [N,K] ----------------
__global__ __launch_bounds__(256) void k_tconv(const float* __restrict__ in,
                                               short* __restrict__ out, int K, int N) {
    __shared__ float tile[64][68];
    int n0 = blockIdx.x * 64, k0 = blockIdx.y * 64;
    int tid = threadIdx.x;
    int c4 = tid & 15, rr = tid >> 4;
    #pragma unroll
    for (int j = 0; j < 4; j++) {
        int row = rr + j * 16;
        float4 vv = *(const float4*)(in + (size_t)(k0 + row) * N + n0 + c4 * 4);
        tile[row][c4*4+0] = vv.x; tile[row][c4*4+1] = vv.y;
        tile[row][c4*4+2] = vv.z; tile[row][c4*4+3] = vv.w;
    }
    __syncthreads();
    #pragma unroll
    for (int j = 0; j < 4; j++) {
        int nrow = rr + j * 16;
        union { unsigned short us[4]; unsigned long long ll; } pk;
        pk.us[0] = f2bf(tile[c4*4+0][nrow]);
        pk.us[1] = f2bf(tile[c4*4+1][nrow]);
        pk.us[2] = f2bf(tile[c4*4+2][nrow]);
        pk.us[3] = f2bf(tile[c4*4+3][nrow]);
        *(unsigned long long*)(out + (size_t)(n0 + nrow) * K + k0 + c4 * 4) = pk.ll;
    }
}

// ---------------- concat qkv bias: [L][3072] ----------------
__global__ __launch_bounds__(256) void k_bcat(const float* __restrict__ bq,
                                              const float* __restrict__ bk,
                                              const float* __restrict__ bv,
                                              float* __restrict__ o) {
    int i = blockIdx.x * 256 + threadIdx.x;
    int l = i / 3072, c = i % 3072;
    float v = (c < 1024) ? bq[l*1024 + c] : ((c < 2048) ? bk[l*1024 + c - 1024] : bv[l*1024 + c - 2048]);
    o[i] = v;
}

// ---------------- V transpose per (b,h) ----------------
__global__ __launch_bounds__(256) void k_vt(const short* __restrict__ qkv, short* __restrict__ vt) {
    int bh = blockIdx.y, b = bh >> 4, h = bh & 15;
    int t0 = blockIdx.x * 64;
    __shared__ short tile[64][72];
    int tid = threadIdx.x;
    int ch = tid & 7, rr = tid >> 3;
    const short* src = qkv + (size_t)b * 1024 * 3072 + 2048 + h * 64;
    #pragma unroll
    for (int j = 0; j < 2; j++) {
        int t = rr + j * 32;
        s16x8 v = *(const s16x8*)&src[(size_t)(t0 + t) * 3072 + ch * 8];
        *(s16x8*)&tile[t][ch * 8] = v;
    }
    __syncthreads();
    #pragma unroll
    for (int j = 0; j < 2; j++) {
        int hd = rr + j * 32;
        union { short ss[8]; s16x8 v; } pk;
        #pragma unroll
        for (int e = 0; e < 8; e++) pk.ss[e] = tile[ch * 8 + e][hd];
        *(s16x8*)&vt[(size_t)(bh * 64 + hd) * 1024 + t0 + ch * 8] = pk.v;
    }
}

// ---------------- GEMM: C[M,N] = A_bf16[M,K] @ Bt_bf16[N,K]^T + bias ----------------
// EPI: 0 = bf16 out; 1 = f32 out + residual; 2 = GELU -> bf16; 3 = f32 out
// MF: wave m-frags. BM = MF*32, BN = 128. 1-D grid, XCD-chunked + m-fastest.
template<int MF, int EPI>
__global__ __launch_bounds__(256) void k_gemm(const short* __restrict__ A, const short* __restrict__ Bt,
                                              const float* bias, const float* res, void* Cout,
                                              int M, int N, int K, int mTiles) {
    constexpr int BM = MF * 32;
    constexpr int IA = BM / 32;              // A gload issues per wave
    __shared__ short lA[BM * 64];
    __shared__ short lB[128 * 64];
    const int tid = threadIdx.x;
    const int l = tid & 63, w = tid >> 6;
    const int wr = w >> 1, wc = w & 1;
    // XCD-chunked (bijective: grid % 8 == 0), m-fastest within chunk
    const int per = gridDim.x >> 3;
    const int s2 = (blockIdx.x & 7) * per + (blockIdx.x >> 3);
    const int nt = s2 / mTiles, mt = s2 - nt * mTiles;
    const int m0 = mt * BM, n0 = nt * 128;
    const int cl = l & 15, rh = l >> 4;
    fx4 acc[MF][4] = {};

    // staging: lane l covers linear LDS slot (row = base + l>>3, chunk = l&7);
    // source chunk pre-XOR'd so read-side XOR sees global chunk kc at slot kc^(row&7)
    const int lr = l >> 3, c8 = l & 7;
    const short* pa[IA];
    const short* pb[4];
    #pragma unroll
    for (int j = 0; j < IA; j++) {
        const int row = w * (BM / 4) + j * 8 + lr;
        pa[j] = A + (size_t)(m0 + row) * K + ((c8 ^ (row & 7)) << 3);
    }
    #pragma unroll
    for (int j = 0; j < 4; j++) {
        const int row = w * 32 + j * 8 + lr;
        pb[j] = Bt + (size_t)(n0 + row) * K + ((c8 ^ (row & 7)) << 3);
    }

    for (int kt = 0; kt < K; kt += 64) {
        #pragma unroll
        for (int j = 0; j < IA; j++)
            gload16(pa[j] + kt, &lA[(w * (BM / 4) + j * 8) * 64]);
        #pragma unroll
        for (int j = 0; j < 4; j++)
            gload16(pb[j] + kt, &lB[(w * 32 + j * 8) * 64]);
        __syncthreads();
        #pragma unroll
        for (int kk = 0; kk < 2; kk++) {
            s16x8 af[MF], bfr[4];
            const int kc = kk * 4 + rh;
            const int ko = (kc ^ (cl & 7)) * 8;
            #pragma unroll
            for (int mf = 0; mf < MF; mf++)
                af[mf] = *(const s16x8*)&lA[(wr * (MF * 16) + mf * 16 + cl) * 64 + ko];
            #pragma unroll
            for (int nf = 0; nf < 4; nf++)
                bfr[nf] = *(const s16x8*)&lB[(wc * 64 + nf * 16 + cl) * 64 + ko];
            #pragma unroll
            for (int mf = 0; mf < MF; mf++)
                #pragma unroll
                for (int nf = 0; nf < 4; nf++)
                    acc[mf][nf] = __builtin_amdgcn_mfma_f32_16x16x32_bf16(af[mf], bfr[nf], acc[mf][nf], 0, 0, 0);
        }
        __syncthreads();
    }
    #pragma unroll
    for (int nf = 0; nf < 4; nf++) {
        const int col = n0 + wc * 64 + nf * 16 + cl;
        const float bv = bias ? bias[col] : 0.0f;
        #pragma unroll
        for (int mf = 0; mf < MF; mf++) {
            const int rbase = m0 + wr * (MF * 16) + mf * 16 + rh * 4;
            #pragma unroll
            for (int r = 0; r < 4; r++) {
                float v = acc[mf][nf][r] + bv;
                const size_t off = (size_t)(rbase + r) * N + col;
                if constexpr (EPI == 0) {
                    ((unsigned short*)Cout)[off] = f2bf(v);
                } else if constexpr (EPI == 1) {
                    ((float*)Cout)[off] = v + res[off];
                } else if constexpr (EPI == 2) {
                    v = 0.5f * v * (1.0f + erff(v * 0.70710678118654752f));
                    ((unsigned short*)Cout)[off] = f2bf(v);
                } else {
                    ((float*)Cout)[off] = v;
                }
            }
        }
    }
}

// ---------------- fused causal attention (flash), 4 waves x 32 q-rows ----------------
__global__ __launch_bounds__(256) void k_attn(const short* __restrict__ qkv,
                                              const short* __restrict__ vt,
                                              short* __restrict__ y) {
    const int bh = blockIdx.y, qt = blockIdx.x;
    const int b = bh >> 4, h = bh & 15;
    const int w = threadIdx.x >> 6, l = threadIdx.x & 63;
    const int cl = l & 15, rh = l >> 4;
    const int q0 = qt * 128 + w * 32;
    const short* qbase = qkv + (size_t)b * 1024 * 3072 + h * 64;
    const short* kbase = qbase + 1024;
    const short* vbase = vt + (size_t)bh * 64 * 1024;
    __shared__ __align__(16) short plds[4][32][72];

    s16x8 qf[2][2];
    #pragma unroll
    for (int mf = 0; mf < 2; mf++)
        #pragma unroll
        for (int kf = 0; kf < 2; kf++)
            qf[mf][kf] = *(const s16x8*)&qbase[(size_t)(q0 + mf * 16 + cl) * 3072 + kf * 32 + rh * 8];

    fx4 o[2][4] = {};
    float mrow[2][4], lrow[2][4];
    #pragma unroll
    for (int mf = 0; mf < 2; mf++)
        #pragma unroll
        for (int r = 0; r < 4; r++) { mrow[mf][r] = -1e30f; lrow[mf][r] = 0.0f; }

    const int ntile = (q0 + 95) >> 6;
    for (int it = 0; it < ntile; it++) {
        const int t0 = it * 64;
        fx4 s[2][4] = {};
        #pragma unroll
        for (int kf = 0; kf < 2; kf++) {
            s16x8 kfr[4];
            #pragma unroll
            for (int nf = 0; nf < 4; nf++)
                kfr[nf] = *(const s16x8*)&kbase[(size_t)(t0 + nf * 16 + cl) * 3072 + kf * 32 + rh * 8];
            #pragma unroll
            for (int mf = 0; mf < 2; mf++)
                #pragma unroll
                for (int nf = 0; nf < 4; nf++)
                    s[mf][nf] = __builtin_amdgcn_mfma_f32_16x16x32_bf16(qf[mf][kf], kfr[nf], s[mf][nf], 0, 0, 0);
        }
        const bool domask = (t0 + 63) > q0;
        #pragma unroll
        for (int mf = 0; mf < 2; mf++) {
            #pragma unroll
            for (int r = 0; r < 4; r++) {
                const int q = q0 + mf * 16 + rh * 4 + r;
                float vals[4];
                float tmax = -1e30f;
                #pragma unroll
                for (int nf = 0; nf < 4; nf++) {
                    float v = s[mf][nf][r] * 0.125f;
                    if (domask && (t0 + nf * 16 + cl) > q) v = -1e30f;
                    vals[nf] = v;
                    tmax = fmaxf(tmax, v);
                }
                #pragma unroll
                for (int mm = 8; mm; mm >>= 1) tmax = fmaxf(tmax, __shfl_xor(tmax, mm));
                const float mold = mrow[mf][r];
                const float mnew = fmaxf(mold, tmax);
                const float alpha = __expf(mold - mnew);
                mrow[mf][r] = mnew;
                float rsum = 0.0f;
                #pragma unroll
                for (int nf = 0; nf < 4; nf++) {
                    float p = __expf(vals[nf] - mnew);
                    rsum += p;
                    plds[w][mf * 16 + rh * 4 + r][nf * 16 + cl] = (short)f2bf(p);
                }
                #pragma unroll
                for (int mm = 8; mm; mm >>= 1) rsum += __shfl_xor(rsum, mm);
                lrow[mf][r] = lrow[mf][r] * alpha + rsum;
                #pragma unroll
                for (int nf = 0; nf < 4; nf++) o[mf][nf][r] *= alpha;
            }
        }
        s16x8 pf[2][2], vf[4][2];
        #pragma unroll
        for (int mf = 0; mf < 2; mf++)
            #pragma unroll
            for (int kf = 0; kf < 2; kf++)
                pf[mf][kf] = *(const s16x8*)&plds[w][mf * 16 + cl][kf * 32 + rh * 8];
        #pragma unroll
        for (int nf = 0; nf < 4; nf++)
            #pragma unroll
            for (int kf = 0; kf < 2; kf++)
                vf[nf][kf] = *(const s16x8*)&vbase[(size_t)(nf * 16 + cl) * 1024 + t0 + kf * 32 + rh * 8];
        #pragma unroll
        for (int mf = 0; mf < 2; mf++)
            #pragma unroll
            for (int nf = 0; nf < 4; nf++)
                #pragma unroll
                for (int kf = 0; kf < 2; kf++)
                    o[mf][nf] = __builtin_amdgcn_mfma_f32_16x16x32_bf16(pf[mf][kf], vf[nf][kf], o[mf][nf], 0, 0, 0);
    }
    #pragma unroll
    for (int mf = 0; mf < 2; mf++) {
        #pragma unroll
        for (int r = 0; r < 4; r++) {
            const float inv = 1.0f / lrow[mf][r];
            const int q = q0 + mf * 16 + rh * 4 + r;
            #pragma unroll
            for (int nf = 0; nf < 4; nf++)
                y[(size_t)(b * 1024 + q) * 1024 + h * 64 + nf * 16 + cl] = (short)f2bf(o[mf][nf][r] * inv);
        }
    }
}

// ---------------- host launcher ----------------
extern "C" void kernel_launch(void* const* d_in, const int* in_sizes, int n_in,
                              void* d_out, int out_size, void* d_ws, size_t ws_size,
                              hipStream_t stream) {
    const int*   idx   = (const int*)d_in[0];
    const float* tok   = (const float*)d_in[1];
    const float* pos   = (const float*)d_in[2];
    const float* ln1w  = (const float*)d_in[3];
    const float* ln1b  = (const float*)d_in[4];
    const float* Wq    = (const float*)d_in[5];
    const float* bq    = (const float*)d_in[6];
    const float* Wk    = (const float*)d_in[7];
    const float* bk    = (const float*)d_in[8];
    const float* Wv    = (const float*)d_in[9];
    const float* bv    = (const float*)d_in[10];
    const float* Wo    = (const float*)d_in[11];
    const float* bo    = (const float*)d_in[12];
    const float* ln2w  = (const float*)d_in[13];
    const float* ln2b  = (const float*)d_in[14];
    const float* W1    = (const float*)d_in[15];
    const float* b1    = (const float*)d_in[16];
    const float* W2    = (const float*)d_in[17];
    const float* b2    = (const float*)d_in[18];
    const float* lnfw  = (const float*)d_in[19];
    const float* lnfb  = (const float*)d_in[20];
    const float* headw = (const float*)d_in[21];

    char* ws = (char*)d_ws;
    size_t off = 0;
    auto nalloc = [&](size_t bytes) -> char* {
        char* p = ws + off;
        off = (off + bytes + 255) & ~(size_t)255;
        return p;
    };
    float* x    = (float*)nalloc((size_t)2048 * 1024 * 4);
    short* h    = (short*)nalloc((size_t)2048 * 1024 * 2);
    short* qkv  = (short*)nalloc((size_t)2048 * 3072 * 2);
    short* vtb  = (short*)nalloc((size_t)32 * 64 * 1024 * 2);
    short* y    = (short*)nalloc((size_t)2048 * 1024 * 2);
    short* u    = (short*)nalloc((size_t)2048 * 4096 * 2);
    short* wqkv = (short*)nalloc((size_t)4 * 3072 * 1024 * 2);
    short* wo   = (short*)nalloc((size_t)4 * 1024 * 1024 * 2);
    short* w1   = (short*)nalloc((size_t)4 * 4096 * 1024 * 2);
    short* w2   = (short*)nalloc((size_t)4 * 1024 * 4096 * 2);
    short* wh   = (short*)nalloc((size_t)32000 * 1024 * 2);
    float* bqkv = (float*)nalloc((size_t)4 * 3072 * 4);

    // ---- weight prep ----
    k_bcat<<<48, 256, 0, stream>>>(bq, bk, bv, bqkv);
    for (int lyr = 0; lyr < 4; lyr++) {
        const size_t wsd = (size_t)lyr * 1024 * 1024;
        k_tconv<<<dim3(16, 16), 256, 0, stream>>>(Wq + wsd, wqkv + (size_t)lyr * 3072 * 1024,               1024, 1024);
        k_tconv<<<dim3(16, 16), 256, 0, stream>>>(Wk + wsd, wqkv + (size_t)lyr * 3072 * 1024 + 1048576,     1024, 1024);
        k_tconv<<<dim3(16, 16), 256, 0, stream>>>(Wv + wsd, wqkv + (size_t)lyr * 3072 * 1024 + 2097152,     1024, 1024);
        k_tconv<<<dim3(16, 16), 256, 0, stream>>>(Wo + wsd, wo + wsd,                                       1024, 1024);
        k_tconv<<<dim3(64, 16), 256, 0, stream>>>(W1 + (size_t)lyr * 4194304, w1 + (size_t)lyr * 4194304,   1024, 4096);
        k_tconv<<<dim3(16, 64), 256, 0, stream>>>(W2 + (size_t)lyr * 4194304, w2 + (size_t)lyr * 4194304,   4096, 1024);
    }
    k_tconv<<<dim3(500, 16), 256, 0, stream>>>(headw, wh, 1024, 32000);

    // ---- forward ----
    k_embed<<<2048, 256, 0, stream>>>(idx, tok, pos, x);
    for (int lyr = 0; lyr < 4; lyr++) {
        k_ln<<<2048, 256, 0, stream>>>(x, ln1w + lyr * 1024, ln1b + lyr * 1024, h);
        k_gemm<4, 0><<<384, 256, 0, stream>>>(h, wqkv + (size_t)lyr * 3072 * 1024, bqkv + lyr * 3072,
                                              nullptr, qkv, 2048, 3072, 1024, 16);
        k_vt<<<dim3(16, 32), 256, 0, stream>>>(qkv, vtb);
        k_attn<<<dim3(8, 32), 256, 0, stream>>>(qkv, vtb, y);
        k_gemm<2, 1><<<256, 256, 0, stream>>>(y, wo + (size_t)lyr * 1024 * 1024, bo + lyr * 1024,
                                              x, x, 2048, 1024, 1024, 32);
        k_ln<<<2048, 256, 0, stream>>>(x, ln2w + lyr * 1024, ln2b + lyr * 1024, h);
        k_gemm<4, 2><<<512, 256, 0, stream>>>(h, w1 + (size_t)lyr * 4194304, b1 + lyr * 4096,
                                              nullptr, u, 2048, 4096, 1024, 16);
        k_gemm<2, 1><<<256, 256, 0, stream>>>(u, w2 + (size_t)lyr * 4194304, b2 + lyr * 1024,
                                              x, x, 2048, 1024, 4096, 32);
    }
    k_ln<<<2048, 256, 0, stream>>>(x, lnfw, lnfb, h);
    k_gemm<4, 3><<<4000, 256, 0, stream>>>(h, wh, nullptr, nullptr, (float*)d_out,
                                           2048, 32000, 1024, 16);
    (void)in_sizes; (void)n_in; (void)out_size; (void)ws_size;
}

// Round 3
// 1207.133 us; speedup vs baseline: 1.0483x; 1.0483x over previous
//
#include <hip/hip_runtime.h>
#include <hip/hip_bf16.h>

// GPT forward: B=2, T=1024, D=1024, H=16, HD=64, L=4, V=32000
// R3: + k_gemm256 (256x256 tile, 8 waves, dbuf LDS, counted vmcnt(8) across raw
//     s_barrier = T3/T4, setprio = T5) for the head GEMM; batched tconv (1 dispatch).

typedef __attribute__((ext_vector_type(8))) short s16x8;
typedef __attribute__((ext_vector_type(4))) float fx4;

__device__ __forceinline__ unsigned short f2bf(float f) {
    union { float f; unsigned int u; } v; v.f = f;
    unsigned int r = v.u + 0x7FFFu + ((v.u >> 16) & 1u);
    return (unsigned short)(r >> 16);
}

__device__ __forceinline__ void gload16(const short* g, short* l) {
    __builtin_amdgcn_global_load_lds((const __attribute__((address_space(1))) void*)g,
                                     (__attribute__((address_space(3))) void*)l, 16, 0, 0);
}

// ---------------- embedding ----------------
__global__ __launch_bounds__(256) void k_embed(const int* __restrict__ idx,
                                               const float* __restrict__ tok,
                                               const float* __restrict__ pos,
                                               float* __restrict__ x) {
    int r = blockIdx.x;
    int t = r & 1023;
    int tokid = idx[r];
    const float4* a = (const float4*)(tok + (size_t)tokid * 1024);
    const float4* p = (const float4*)(pos + (size_t)t * 1024);
    float4* o = (float4*)(x + (size_t)r * 1024);
    int i = threadIdx.x;
    float4 va = a[i], vp = p[i];
    va.x += vp.x; va.y += vp.y; va.z += vp.z; va.w += vp.w;
    o[i] = va;
}

// ---------------- layernorm (row of 1024), bf16 out ----------------
__global__ __launch_bounds__(256) void k_ln(const float* __restrict__ x,
                                            const float* __restrict__ w,
                                            const float* __restrict__ b,
                                            short* __restrict__ out) {
    int r = blockIdx.x;
    int tid = threadIdx.x;
    float4 v = ((const float4*)(x + (size_t)r * 1024))[tid];
    float s = v.x + v.y + v.z + v.w;
    float ss = v.x*v.x + v.y*v.y + v.z*v.z + v.w*v.w;
    __shared__ float red[8];
    #pragma unroll
    for (int off = 32; off; off >>= 1) { s += __shfl_down(s, off); ss += __shfl_down(ss, off); }
    int wid = tid >> 6;
    if ((tid & 63) == 0) { red[wid] = s; red[4 + wid] = ss; }
    __syncthreads();
    s = red[0] + red[1] + red[2] + red[3];
    ss = red[4] + red[5] + red[6] + red[7];
    float mean = s * (1.0f / 1024.0f);
    float var = ss * (1.0f / 1024.0f) - mean * mean;
    float rstd = rsqrtf(var + 1e-5f);
    float4 wv = ((const float4*)w)[tid];
    float4 bv = ((const float4*)b)[tid];
    union { unsigned short us[4]; unsigned long long ll; } pk;
    pk.us[0] = f2bf((v.x - mean) * rstd * wv.x + bv.x);
    pk.us[1] = f2bf((v.y - mean) * rstd * wv.y + bv.y);
    pk.us[2] = f2bf((v.z - mean) * rstd * wv.z + bv.z);
    pk.us[3] = f2bf((v.w - mean) * rstd * wv.w + bv.w);
    ((unsigned long long*)(out + (size_t)r * 1024))[tid] = pk.ll;
}

// ---------------- batched transpose+convert: all weights, one dispatch ----------------
// segments (64x64 tiles): [0,4096) Wq/Wk/Wv/Wo (1024 each), [4096,8192) W1,
// [8192,12288) W2, [12288,20288) head
__global__ __launch_bounds__(256) void k_tconv_all(
        const float* __restrict__ Wq, const float* __restrict__ Wk,
        const float* __restrict__ Wv, const float* __restrict__ Wo,
        const float* __restrict__ W1, const float* __restrict__ W2,
        const float* __restrict__ Wh,
        short* __restrict__ wqkv, short* __restrict__ wo,
        short* __restrict__ w1, short* __restrict__ w2, short* __restrict__ wh) {
    const int bid = blockIdx.x;
    const float* src; short* dst; int K, N, tile;
    if (bid < 4096) {
        int seg = bid >> 10;           // 0=q 1=k 2=v 3=o
        int r = bid & 1023;
        int l = r >> 8; tile = r & 255;
        K = 1024; N = 1024;
        if (seg == 0)      { src = Wq + (size_t)l * 1048576; dst = wqkv + (size_t)l * 3145728; }
        else if (seg == 1) { src = Wk + (size_t)l * 1048576; dst = wqkv + (size_t)l * 3145728 + 1048576; }
        else if (seg == 2) { src = Wv + (size_t)l * 1048576; dst = wqkv + (size_t)l * 3145728 + 2097152; }
        else               { src = Wo + (size_t)l * 1048576; dst = wo + (size_t)l * 1048576; }
    } else if (bid < 8192) {
        int r = bid - 4096; int l = r >> 10; tile = r & 1023;
        K = 1024; N = 4096; src = W1 + (size_t)l * 4194304; dst = w1 + (size_t)l * 4194304;
    } else if (bid < 12288) {
        int r = bid - 8192; int l = r >> 10; tile = r & 1023;
        K = 4096; N = 1024; src = W2 + (size_t)l * 4194304; dst = w2 + (size_t)l * 4194304;
    } else {
        tile = bid - 12288; K = 1024; N = 32000; src = Wh; dst = wh;
    }
    const int nTiles = N >> 6;
    const int kt = tile / nTiles, ntl = tile - kt * nTiles;
    const int n0 = ntl * 64, k0 = kt * 64;

    __shared__ float tl[64][65];
    const int tid = threadIdx.x;
    const int c4 = tid & 15, rr = tid >> 4;
    #pragma unroll
    for (int j = 0; j < 4; j++) {
        int row = rr + j * 16;
        float4 vv = *(const float4*)(src + (size_t)(k0 + row) * N + n0 + c4 * 4);
        tl[row][c4*4+0] = vv.x; tl[row][c4*4+1] = vv.y;
        tl[row][c4*4+2] = vv.z; tl[row][c4*4+3] = vv.w;
    }
    __syncthreads();
    const int c8 = tid & 7, r2 = tid >> 3;
    #pragma unroll
    for (int j = 0; j < 2; j++) {
        int nrow = r2 + j * 32;
        union { unsigned short us[8]; s16x8 v; } pk;
        #pragma unroll
        for (int e = 0; e < 8; e++) pk.us[e] = f2bf(tl[c8*8+e][nrow]);
        *(s16x8*)&dst[(size_t)(n0 + nrow) * K + k0 + c8 * 8] = pk.v;
    }
}

// ---------------- concat qkv bias: [L][3072] ----------------
__global__ __launch_bounds__(256) void k_bcat(const float* __restrict__ bq,
                                              const float* __restrict__ bk,
                                              const float* __restrict__ bv,
                                              float* __restrict__ o) {
    int i = blockIdx.x * 256 + threadIdx.x;
    int l = i / 3072, c = i % 3072;
    float v = (c < 1024) ? bq[l*1024 + c] : ((c < 2048) ? bk[l*1024 + c - 1024] : bv[l*1024 + c - 2048]);
    o[i] = v;
}

// ---------------- V transpose per (b,h) ----------------
__global__ __launch_bounds__(256) void k_vt(const short* __restrict__ qkv, short* __restrict__ vt) {
    int bh = blockIdx.y, b = bh >> 4, h = bh & 15;
    int t0 = blockIdx.x * 64;
    __shared__ short tile[64][72];
    int tid = threadIdx.x;
    int ch = tid & 7, rr = tid >> 3;
    const short* src = qkv + (size_t)b * 1024 * 3072 + 2048 + h * 64;
    #pragma unroll
    for (int j = 0; j < 2; j++) {
        int t = rr + j * 32;
        s16x8 v = *(const s16x8*)&src[(size_t)(t0 + t) * 3072 + ch * 8];
        *(s16x8*)&tile[t][ch * 8] = v;
    }
    __syncthreads();
    #pragma unroll
    for (int j = 0; j < 2; j++) {
        int hd = rr + j * 32;
        union { short ss[8]; s16x8 v; } pk;
        #pragma unroll
        for (int e = 0; e < 8; e++) pk.ss[e] = tile[ch * 8 + e][hd];
        *(s16x8*)&vt[(size_t)(bh * 64 + hd) * 1024 + t0 + ch * 8] = pk.v;
    }
}

// ---------------- 128-class GEMM (m97 structure), EPI variants ----------------
// EPI: 0 = bf16 out; 1 = f32 out + residual; 2 = GELU -> bf16; 3 = f32 out
template<int MF, int EPI>
__global__ __launch_bounds__(256) void k_gemm(const short* __restrict__ A, const short* __restrict__ Bt,
                                              const float* bias, const float* res, void* Cout,
                                              int M, int N, int K, int mTiles) {
    constexpr int BM = MF * 32;
    constexpr int IA = BM / 32;
    __shared__ __align__(16) short lA[BM * 64];
    __shared__ __align__(16) short lB[128 * 64];
    const int tid = threadIdx.x;
    const int l = tid & 63, w = tid >> 6;
    const int wr = w >> 1, wc = w & 1;
    const int per = gridDim.x >> 3;
    const int s2 = (blockIdx.x & 7) * per + (blockIdx.x >> 3);
    const int nt = s2 / mTiles, mt = s2 - nt * mTiles;
    const int m0 = mt * BM, n0 = nt * 128;
    const int cl = l & 15, rh = l >> 4;
    fx4 acc[MF][4] = {};

    const int lr = l >> 3, c8 = l & 7;
    const short* pa[IA];
    const short* pb[4];
    #pragma unroll
    for (int j = 0; j < IA; j++) {
        const int row = w * (BM / 4) + j * 8 + lr;
        pa[j] = A + (size_t)(m0 + row) * K + ((c8 ^ (row & 7)) << 3);
    }
    #pragma unroll
    for (int j = 0; j < 4; j++) {
        const int row = w * 32 + j * 8 + lr;
        pb[j] = Bt + (size_t)(n0 + row) * K + ((c8 ^ (row & 7)) << 3);
    }

    for (int kt = 0; kt < K; kt += 64) {
        #pragma unroll
        for (int j = 0; j < IA; j++)
            gload16(pa[j] + kt, &lA[(w * (BM / 4) + j * 8) * 64]);
        #pragma unroll
        for (int j = 0; j < 4; j++)
            gload16(pb[j] + kt, &lB[(w * 32 + j * 8) * 64]);
        __syncthreads();
        #pragma unroll
        for (int kk = 0; kk < 2; kk++) {
            s16x8 af[MF], bfr[4];
            const int kc = kk * 4 + rh;
            const int ko = (kc ^ (cl & 7)) * 8;
            #pragma unroll
            for (int mf = 0; mf < MF; mf++)
                af[mf] = *(const s16x8*)&lA[(wr * (MF * 16) + mf * 16 + cl) * 64 + ko];
            #pragma unroll
            for (int nf = 0; nf < 4; nf++)
                bfr[nf] = *(const s16x8*)&lB[(wc * 64 + nf * 16 + cl) * 64 + ko];
            #pragma unroll
            for (int mf = 0; mf < MF; mf++)
                #pragma unroll
                for (int nf = 0; nf < 4; nf++)
                    acc[mf][nf] = __builtin_amdgcn_mfma_f32_16x16x32_bf16(af[mf], bfr[nf], acc[mf][nf], 0, 0, 0);
        }
        __syncthreads();
    }
    #pragma unroll
    for (int nf = 0; nf < 4; nf++) {
        const int col = n0 + wc * 64 + nf * 16 + cl;
        const float bv = bias ? bias[col] : 0.0f;
        #pragma unroll
        for (int mf = 0; mf < MF; mf++) {
            const int rbase = m0 + wr * (MF * 16) + mf * 16 + rh * 4;
            #pragma unroll
            for (int r = 0; r < 4; r++) {
                float v = acc[mf][nf][r] + bv;
                const size_t off = (size_t)(rbase + r) * N + col;
                if constexpr (EPI == 0) {
                    ((unsigned short*)Cout)[off] = f2bf(v);
                } else if constexpr (EPI == 1) {
                    ((float*)Cout)[off] = v + res[off];
                } else if constexpr (EPI == 2) {
                    v = 0.5f * v * (1.0f + erff(v * 0.70710678118654752f));
                    ((unsigned short*)Cout)[off] = f2bf(v);
                } else {
                    ((float*)Cout)[off] = v;
                }
            }
        }
    }
}

// ---------------- 256x256 GEMM, counted-vmcnt double-buffered pipeline ----------------
// 8 waves (2Mx4N), BK=64, LDS 128KiB (2 bufs x (A 32K + B 32K)).
// Stage tile t+1 issued BEFORE waiting tile t: s_waitcnt vmcnt(8) + raw s_barrier
// (8 loads stay in flight across the barrier). f32 output, no bias (head GEMM).
__global__ __launch_bounds__(512, 2) void k_gemm256(const short* __restrict__ A,
                                                    const short* __restrict__ Bt,
                                                    float* __restrict__ C,
                                                    int M, int N, int K, int mTiles) {
    __shared__ __align__(16) short lA[2][256 * 64];
    __shared__ __align__(16) short lB[2][256 * 64];
    const int tid = threadIdx.x;
    const int l = tid & 63, w = tid >> 6;
    const int wr = w >> 2, wc = w & 3;          // 2 x 4 waves
    const int per = gridDim.x >> 3;
    const int s2 = (blockIdx.x & 7) * per + (blockIdx.x >> 3);
    const int nt0 = s2 / mTiles, mt = s2 - nt0 * mTiles;
    const int m0 = mt * 256, n0 = nt0 * 256;
    const int cl = l & 15, rh = l >> 4;

    fx4 acc[8][4] = {};

    // staging geometry: issue j covers rows j*64 + (tid>>3), chunk tid&7 (16B)
    const int srow = tid >> 3, sc8 = tid & 7;
    const short* pa[4];
    const short* pb[4];
    #pragma unroll
    for (int j = 0; j < 4; j++) {
        const int row = j * 64 + srow;
        pa[j] = A + (size_t)(m0 + row) * K + ((sc8 ^ (row & 7)) << 3);
        pb[j] = Bt + (size_t)(n0 + row) * K + ((sc8 ^ (row & 7)) << 3);
    }
    const int ldsoff = w * 512;                 // wave-uniform lds base (shorts)

    auto stage = [&](int nb, int kt2) {
        #pragma unroll
        for (int j = 0; j < 4; j++) {
            gload16(pa[j] + kt2, &lA[nb][j * 4096 + ldsoff]);
            gload16(pb[j] + kt2, &lB[nb][j * 4096 + ldsoff]);
        }
    };

    const int NT = K >> 6;
    stage(0, 0);
    for (int t = 0; t < NT; ++t) {
        const int cur = t & 1;
        if (t + 1 < NT) {
            stage(cur ^ 1, (t + 1) << 6);
            asm volatile("s_waitcnt vmcnt(8)" ::: "memory");
        } else {
            asm volatile("s_waitcnt vmcnt(0)" ::: "memory");
        }
        __builtin_amdgcn_s_barrier();
        asm volatile("" ::: "memory");          // fence: no ds_read hoist above barrier
        const short* bufA = lA[cur];
        const short* bufB = lB[cur];
        #pragma unroll
        for (int q = 0; q < 4; ++q) {           // quadrant: 2 m-frags x 4 n-frags x K64
            s16x8 af[2][2], bf[4][2];
            #pragma unroll
            for (int i = 0; i < 2; ++i)
                #pragma unroll
                for (int kk = 0; kk < 2; ++kk) {
                    const int row = wr * 128 + (q * 2 + i) * 16 + cl;
                    const int ko = (((kk * 4 + rh) ^ (cl & 7)) << 3);
                    af[i][kk] = *(const s16x8*)&bufA[row * 64 + ko];
                }
            #pragma unroll
            for (int nf = 0; nf < 4; ++nf)
                #pragma unroll
                for (int kk = 0; kk < 2; ++kk) {
                    const int row = wc * 64 + nf * 16 + cl;
                    const int ko = (((kk * 4 + rh) ^ (cl & 7)) << 3);
                    bf[nf][kk] = *(const s16x8*)&bufB[row * 64 + ko];
                }
            __builtin_amdgcn_s_setprio(1);
            #pragma unroll
            for (int i = 0; i < 2; ++i)
                #pragma unroll
                for (int nf = 0; nf < 4; ++nf) {
                    acc[q*2+i][nf] = __builtin_amdgcn_mfma_f32_16x16x32_bf16(af[i][0], bf[nf][0], acc[q*2+i][nf], 0, 0, 0);
                    acc[q*2+i][nf] = __builtin_amdgcn_mfma_f32_16x16x32_bf16(af[i][1], bf[nf][1], acc[q*2+i][nf], 0, 0, 0);
                }
            __builtin_amdgcn_s_setprio(0);
        }
        asm volatile("" ::: "memory");
        __builtin_amdgcn_s_barrier();           // buf[cur] free for overwrite next iter
        asm volatile("" ::: "memory");
    }
    #pragma unroll
    for (int mf = 0; mf < 8; ++mf) {
        const int rbase = m0 + wr * 128 + mf * 16 + rh * 4;
        #pragma unroll
        for (int nf = 0; nf < 4; ++nf) {
            const int col = n0 + wc * 64 + nf * 16 + cl;
            #pragma unroll
            for (int r = 0; r < 4; ++r)
                C[(size_t)(rbase + r) * N + col] = acc[mf][nf][r];
        }
    }
}

// ---------------- fused causal attention (flash), 4 waves x 32 q-rows ----------------
__global__ __launch_bounds__(256) void k_attn(const short* __restrict__ qkv,
                                              const short* __restrict__ vt,
                                              short* __restrict__ y) {
    const int bh = blockIdx.y, qt = blockIdx.x;
    const int b = bh >> 4, h = bh & 15;
    const int w = threadIdx.x >> 6, l = threadIdx.x & 63;
    const int cl = l & 15, rh = l >> 4;
    const int q0 = qt * 128 + w * 32;
    const short* qbase = qkv + (size_t)b * 1024 * 3072 + h * 64;
    const short* kbase = qbase + 1024;
    const short* vbase = vt + (size_t)bh * 64 * 1024;
    __shared__ __align__(16) short plds[4][32][72];

    s16x8 qf[2][2];
    #pragma unroll
    for (int mf = 0; mf < 2; mf++)
        #pragma unroll
        for (int kf = 0; kf < 2; kf++)
            qf[mf][kf] = *(const s16x8*)&qbase[(size_t)(q0 + mf * 16 + cl) * 3072 + kf * 32 + rh * 8];

    fx4 o[2][4] = {};
    float mrow[2][4], lrow[2][4];
    #pragma unroll
    for (int mf = 0; mf < 2; mf++)
        #pragma unroll
        for (int r = 0; r < 4; r++) { mrow[mf][r] = -1e30f; lrow[mf][r] = 0.0f; }

    const int ntile = (q0 + 95) >> 6;
    for (int it = 0; it < ntile; it++) {
        const int t0 = it * 64;
        fx4 s[2][4] = {};
        #pragma unroll
        for (int kf = 0; kf < 2; kf++) {
            s16x8 kfr[4];
            #pragma unroll
            for (int nf = 0; nf < 4; nf++)
                kfr[nf] = *(const s16x8*)&kbase[(size_t)(t0 + nf * 16 + cl) * 3072 + kf * 32 + rh * 8];
            #pragma unroll
            for (int mf = 0; mf < 2; mf++)
                #pragma unroll
                for (int nf = 0; nf < 4; nf++)
                    s[mf][nf] = __builtin_amdgcn_mfma_f32_16x16x32_bf16(qf[mf][kf], kfr[nf], s[mf][nf], 0, 0, 0);
        }
        const bool domask = (t0 + 63) > q0;
        #pragma unroll
        for (int mf = 0; mf < 2; mf++) {
            #pragma unroll
            for (int r = 0; r < 4; r++) {
                const int q = q0 + mf * 16 + rh * 4 + r;
                float vals[4];
                float tmax = -1e30f;
                #pragma unroll
                for (int nf = 0; nf < 4; nf++) {
                    float v = s[mf][nf][r] * 0.125f;
                    if (domask && (t0 + nf * 16 + cl) > q) v = -1e30f;
                    vals[nf] = v;
                    tmax = fmaxf(tmax, v);
                }
                #pragma unroll
                for (int mm = 8; mm; mm >>= 1) tmax = fmaxf(tmax, __shfl_xor(tmax, mm));
                const float mold = mrow[mf][r];
                const float mnew = fmaxf(mold, tmax);
                const float alpha = __expf(mold - mnew);
                mrow[mf][r] = mnew;
                float rsum = 0.0f;
                #pragma unroll
                for (int nf = 0; nf < 4; nf++) {
                    float p = __expf(vals[nf] - mnew);
                    rsum += p;
                    plds[w][mf * 16 + rh * 4 + r][nf * 16 + cl] = (short)f2bf(p);
                }
                #pragma unroll
                for (int mm = 8; mm; mm >>= 1) rsum += __shfl_xor(rsum, mm);
                lrow[mf][r] = lrow[mf][r] * alpha + rsum;
                #pragma unroll
                for (int nf = 0; nf < 4; nf++) o[mf][nf][r] *= alpha;
            }
        }
        s16x8 pf[2][2], vf[4][2];
        #pragma unroll
        for (int mf = 0; mf < 2; mf++)
            #pragma unroll
            for (int kf = 0; kf < 2; kf++)
                pf[mf][kf] = *(const s16x8*)&plds[w][mf * 16 + cl][kf * 32 + rh * 8];
        #pragma unroll
        for (int nf = 0; nf < 4; nf++)
            #pragma unroll
            for (int kf = 0; kf < 2; kf++)
                vf[nf][kf] = *(const s16x8*)&vbase[(size_t)(nf * 16 + cl) * 1024 + t0 + kf * 32 + rh * 8];
        #pragma unroll
        for (int mf = 0; mf < 2; mf++)
            #pragma unroll
            for (int nf = 0; nf < 4; nf++)
                #pragma unroll
                for (int kf = 0; kf < 2; kf++)
                    o[mf][nf] = __builtin_amdgcn_mfma_f32_16x16x32_bf16(pf[mf][kf], vf[nf][kf], o[mf][nf], 0, 0, 0);
    }
    #pragma unroll
    for (int mf = 0; mf < 2; mf++) {
        #pragma unroll
        for (int r = 0; r < 4; r++) {
            const float inv = 1.0f / lrow[mf][r];
            const int q = q0 + mf * 16 + rh * 4 + r;
            #pragma unroll
            for (int nf = 0; nf < 4; nf++)
                y[(size_t)(b * 1024 + q) * 1024 + h * 64 + nf * 16 + cl] = (short)f2bf(o[mf][nf][r] * inv);
        }
    }
}

// ---------------- host launcher ----------------
extern "C" void kernel_launch(void* const* d_in, const int* in_sizes, int n_in,
                              void* d_out, int out_size, void* d_ws, size_t ws_size,
                              hipStream_t stream) {
    const int*   idx   = (const int*)d_in[0];
    const float* tok   = (const float*)d_in[1];
    const float* pos   = (const float*)d_in[2];
    const float* ln1w  = (const float*)d_in[3];
    const float* ln1b  = (const float*)d_in[4];
    const float* Wq    = (const float*)d_in[5];
    const float* bq    = (const float*)d_in[6];
    const float* Wk    = (const float*)d_in[7];
    const float* bk    = (const float*)d_in[8];
    const float* Wv    = (const float*)d_in[9];
    const float* bv    = (const float*)d_in[10];
    const float* Wo    = (const float*)d_in[11];
    const float* bo    = (const float*)d_in[12];
    const float* ln2w  = (const float*)d_in[13];
    const float* ln2b  = (const float*)d_in[14];
    const float* W1    = (const float*)d_in[15];
    const float* b1    = (const float*)d_in[16];
    const float* W2    = (const float*)d_in[17];
    const float* b2    = (const float*)d_in[18];
    const float* lnfw  = (const float*)d_in[19];
    const float* lnfb  = (const float*)d_in[20];
    const float* headw = (const float*)d_in[21];

    char* ws = (char*)d_ws;
    size_t off = 0;
    auto nalloc = [&](size_t bytes) -> char* {
        char* p = ws + off;
        off = (off + bytes + 255) & ~(size_t)255;
        return p;
    };
    float* x    = (float*)nalloc((size_t)2048 * 1024 * 4);
    short* h    = (short*)nalloc((size_t)2048 * 1024 * 2);
    short* qkv  = (short*)nalloc((size_t)2048 * 3072 * 2);
    short* vtb  = (short*)nalloc((size_t)32 * 64 * 1024 * 2);
    short* y    = (short*)nalloc((size_t)2048 * 1024 * 2);
    short* u    = (short*)nalloc((size_t)2048 * 4096 * 2);
    short* wqkv = (short*)nalloc((size_t)4 * 3072 * 1024 * 2);
    short* wo   = (short*)nalloc((size_t)4 * 1024 * 1024 * 2);
    short* w1   = (short*)nalloc((size_t)4 * 4096 * 1024 * 2);
    short* w2   = (short*)nalloc((size_t)4 * 1024 * 4096 * 2);
    short* wh   = (short*)nalloc((size_t)32000 * 1024 * 2);
    float* bqkv = (float*)nalloc((size_t)4 * 3072 * 4);

    // ---- weight prep: one batched dispatch (+ bias concat) ----
    k_bcat<<<48, 256, 0, stream>>>(bq, bk, bv, bqkv);
    k_tconv_all<<<20288, 256, 0, stream>>>(Wq, Wk, Wv, Wo, W1, W2, headw,
                                           wqkv, wo, w1, w2, wh);

    // ---- forward ----
    k_embed<<<2048, 256, 0, stream>>>(idx, tok, pos, x);
    for (int lyr = 0; lyr < 4; lyr++) {
        k_ln<<<2048, 256, 0, stream>>>(x, ln1w + lyr * 1024, ln1b + lyr * 1024, h);
        k_gemm<4, 0><<<384, 256, 0, stream>>>(h, wqkv + (size_t)lyr * 3072 * 1024, bqkv + lyr * 3072,
                                              nullptr, qkv, 2048, 3072, 1024, 16);
        k_vt<<<dim3(16, 32), 256, 0, stream>>>(qkv, vtb);
        k_attn<<<dim3(8, 32), 256, 0, stream>>>(qkv, vtb, y);
        k_gemm<2, 1><<<256, 256, 0, stream>>>(y, wo + (size_t)lyr * 1024 * 1024, bo + lyr * 1024,
                                              x, x, 2048, 1024, 1024, 32);
        k_ln<<<2048, 256, 0, stream>>>(x, ln2w + lyr * 1024, ln2b + lyr * 1024, h);
        k_gemm<4, 2><<<512, 256, 0, stream>>>(h, w1 + (size_t)lyr * 4194304, b1 + lyr * 4096,
                                              nullptr, u, 2048, 4096, 1024, 16);
        k_gemm<2, 1><<<256, 256, 0, stream>>>(u, w2 + (size_t)lyr * 4194304, b2 + lyr * 1024,
                                              x, x, 2048, 1024, 4096, 32);
    }
    k_ln<<<2048, 256, 0, stream>>>(x, lnfw, lnfb, h);
    k_gemm256<<<1000, 512, 0, stream>>>(h, wh, (float*)d_out, 2048, 32000, 1024, 8);
    (void)in_sizes; (void)n_in; (void)out_size; (void)ws_size;
}